// Round 14
// baseline (266.918 us; speedup 1.0000x reference)
//
#include <hip/hip_runtime.h>
#include <hip/hip_bf16.h>

// GVPDynamicProjection: N=10000, C=2, SI=128, VI=16, H=4, R=32, SH=32, VH=4
// Inputs/outputs: float32. R14 vs R13 (240.8 us): single change — kAttn
// 512thr/128rows (157 blocks = 61% of CUs) -> 256thr/64rows (313 blocks, all
// CUs). LDS-issue model: 10.9M wave-LDS-cycles total; /157 CUs = 29us floor,
// /256 CUs = 18us. Body unchanged (R9-proven; <=~80 live floats — R8/R10
// measured the >100-float variants spill/stall).
// kA parked at its ~50us plateau (R7/R9/R13: occupancy 32/44/57% all ~49-63;
// weight-stream latency + barrier structure, not wave count).

#define N_  10000
#define C_  2
#define SI_ 128
#define VI_ 16
#define H_  4
#define R_  32
#define SH_ 32
#define VH_ 4
#define NC_ (N_*C_)

typedef const float* __restrict__ fptr;

__device__ __forceinline__ float sigm(float x){ return 1.f/(1.f+__expf(-x)); }

// ---------------- ws layout (float offsets) ----------------
#define OFF_LG   0
#define OFF_EQH  640000
#define OFF_SG   2640000
#define OFF_TKH  2651520
#define OFF_TEK  2657664
#define OFF_TVS  2657920
#define OFF_TVV  2666112

#define SGSTRIDE_ 180

// ================= kernel A: per-row logits + q-path =================
// 256 threads, 8 rows/block; grid = NC_/8 = 2500
__global__ __launch_bounds__(256) void kA(
    fptr s, fptr v,
    fptr wp_wh, fptr wp_ws_w, fptr wp_ws_b,
    fptr q_wh, fptr q_ws_w, fptr q_ws_b, fptr q_wv, fptr q_wsv_w, fptr q_wsv_b,
    fptr attn_wh, fptr attn_ws_w,
    float* __restrict__ pexp, float* __restrict__ eqh,
    float* __restrict__ sgz)
{
  __shared__ __align__(16) float ARENA[160*12];
  __shared__ __align__(16) float VVs[8*48];
  __shared__ __align__(16) float VHQ[8*48];
  __shared__ __align__(16) float SO[8*128];
  __shared__ __align__(16) float GATE[8*16];
  __shared__ __align__(16) float QV[8*48];
  float* const XT  = ARENA;
  float* const SIG = ARENA;

  const int tid  = threadIdx.x;
  const int row0 = blockIdx.x * 8;

  if (blockIdx.x == 0){
    for (int i = tid; i < 64*SGSTRIDE_; i += 256) sgz[i] = 0.f;
  }

  for (int idx = tid; idx < 8*128; idx += 256){
    int r = idx >> 7, j = idx & 127;
    XT[j*12 + r] = s[(row0+r)*128 + j];
  }
  for (int idx = tid; idx < 8*48; idx += 256){
    int r = idx / 48, k = idx - r*48;
    VVs[r*48 + k] = v[(row0+r)*48 + k];
  }
  __syncthreads();

  {
    int r = tid >> 5, ii = tid & 31, path = ii >> 4, i = ii & 15;
    fptr wh = path ? wp_wh : q_wh;
    float h0=0.f, h1=0.f, h2=0.f;
    #pragma unroll
    for (int j = 0; j < 16; j++){
      float w = wh[j*16 + i];
      h0 = fmaf(VVs[r*48 + j*3 + 0], w, h0);
      h1 = fmaf(VVs[r*48 + j*3 + 1], w, h1);
      h2 = fmaf(VVs[r*48 + j*3 + 2], w, h2);
    }
    float vn = sqrtf(fmaxf(h0*h0 + h1*h1 + h2*h2, 1e-8f));
    if (!path){
      VHQ[r*48 +  0 + i] = h0;
      VHQ[r*48 + 16 + i] = h1;
      VHQ[r*48 + 32 + i] = h2;
      XT[(128+i)*12 + r] = vn;
    } else {
      XT[(144+i)*12 + r] = vn;
    }
  }
  __syncthreads();

  const int colA = tid & 127, rgA = tid >> 7;
  float acc[4];
  {
    float bqs = q_ws_b[colA];
    #pragma unroll
    for (int k = 0; k < 4; k++) acc[k] = bqs;
    #pragma unroll 8
    for (int j = 0; j < 144; j++){
      float w = q_ws_w[j*128 + colA];
      float4 x0 = *(const float4*)&XT[j*12 + rgA*4];
      acc[0] = fmaf(x0.x, w, acc[0]); acc[1] = fmaf(x0.y, w, acc[1]);
      acc[2] = fmaf(x0.z, w, acc[2]); acc[3] = fmaf(x0.w, w, acc[3]);
    }
  }
  {
    const int col = tid & 31, rg = tid >> 5;
    float a0 = wp_ws_b[col];
    #pragma unroll 8
    for (int j = 0; j < 144; j++){
      int jj = (j < 128) ? j : (j + 16);
      a0 = fmaf(XT[jj*12 + rg], wp_ws_w[j*32 + col], a0);
    }
    const int c = rg & 1, n = (row0 + rg) >> 1;
    pexp[(c*32 + col)*N_ + n] = __expf(a0);
  }
  __syncthreads();

  #pragma unroll
  for (int k = 0; k < 4; k++){
    float so = acc[k];
    float sg_ = sigm(so);
    SIG[(rgA*4 + k)*128 + colA] = sg_;
    SO [(rgA*4 + k)*128 + colA] = so * sg_;
  }
  __syncthreads();

  if (tid < 128){
    const int r = tid >> 4, g = tid & 15;
    float ga = q_wsv_b[g];
    #pragma unroll 8
    for (int o = 0; o < 128; o += 4){
      float4 s4 = *(const float4*)&SIG[r*128 + o];
      ga = fmaf(s4.x, q_wsv_w[(o+0)*16 + g], ga);
      ga = fmaf(s4.y, q_wsv_w[(o+1)*16 + g], ga);
      ga = fmaf(s4.z, q_wsv_w[(o+2)*16 + g], ga);
      ga = fmaf(s4.w, q_wsv_w[(o+3)*16 + g], ga);
    }
    GATE[r*16 + g] = sigm(ga);
  } else if (tid < 160){
    const int t2 = tid - 128, r = t2 >> 2, h = t2 & 3;
    float e = 0.f;
    #pragma unroll
    for (int t = 0; t < 32; t++)
      e = fmaf(SO[r*128 + h*32 + t], attn_ws_w[t], e);
    eqh[(row0 + r)*100 + h] = e;
  }
  __syncthreads();

  for (int t = tid; t < 8*48; t += 256){
    int r = t / 48, k = t - r*48, i = k / 3, d = k - i*3;
    float a = 0.f;
    #pragma unroll
    for (int j = 0; j < 16; j++)
      a = fmaf(VHQ[r*48 + d*16 + j], q_wv[j*16 + i], a);
    QV[r*48 + k] = a * GATE[r*16 + i];
  }
  __syncthreads();

  for (int t = tid; t < 8*96; t += 256){
    int r = t / 96, k = t - r*96;
    int h = k / 24, rem = k - h*24, d = rem >> 3, ee = rem & 7;
    float a = 0.f;
    #pragma unroll
    for (int i = 0; i < 4; i++)
      a = fmaf(QV[r*48 + (h*4 + i)*3 + d], attn_wh[i*8 + ee], a);
    eqh[(row0 + r)*100 + 8 + k] = a;
  }
}

// ===== kAccum: weighted sums via atomics, 800 blocks = 3200 waves ==========
__global__ __launch_bounds__(256) void kAccum(const float* __restrict__ pexp,
                                              fptr s, fptr v,
                                              float* __restrict__ sg)
{
  const int b = blockIdx.x;
  const int c = b & 1, ah = (b >> 1) & 1, chunk = b >> 2;
  const int n0 = chunk * 50;
  const int tid = threadIdx.x;
  const int ag = tid >> 6, dl = tid & 63;
  const int abase = ah*16 + ag*4;

  const float* pb = pexp + (c*32 + abase)*N_;
  float acc[4][3] = {};
  float dn[4] = {};

  #pragma unroll 2
  for (int n = n0; n < n0 + 50; n++){
    const int rc = n*2 + c;
    float pw[4];
    #pragma unroll
    for (int aa = 0; aa < 4; aa++){
      pw[aa] = pb[aa*N_ + n];
      dn[aa] += pw[aa];
    }
    #pragma unroll
    for (int dd = 0; dd < 3; dd++){
      int d = dl + 64*dd;
      if (d < 176){
        float xv = (d < 128) ? s[rc*128 + d] : v[rc*48 + d - 128];
        #pragma unroll
        for (int aa = 0; aa < 4; aa++)
          acc[aa][dd] = fmaf(pw[aa], xv, acc[aa][dd]);
      }
    }
  }
  #pragma unroll
  for (int aa = 0; aa < 4; aa++){
    const int base = (c*32 + abase + aa)*SGSTRIDE_;
    #pragma unroll
    for (int dd = 0; dd < 3; dd++){
      int d = dl + 64*dd;
      if (d < 176) atomicAdd(&sg[base + d], acc[aa][dd]);
    }
    if (dl == 0) atomicAdd(&sg[base + 176], dn[aa]);
  }
}

// ================= kSmall: normalize + k/vv GVP + attn tables ===============
__global__ __launch_bounds__(256) void kSmall(
    const float* __restrict__ sg,
    fptr k_wh, fptr k_ws_w, fptr k_ws_b, fptr k_wv, fptr k_wsv_w, fptr k_wsv_b,
    fptr vv_wh, fptr vv_ws_w, fptr vv_ws_b, fptr vv_wv, fptr vv_wsv_w, fptr vv_wsv_b,
    fptr attn_wh, fptr attn_ws_w,
    float* __restrict__ tkh, float* __restrict__ tek,
    float* __restrict__ tvs, float* __restrict__ tvv)
{
  const int b = blockIdx.x, r = b >> 1, c = b & 1;
  const int tid = threadIdx.x;
  __shared__ float X[176];
  __shared__ float VN[2][16];
  __shared__ float VH[2][48];
  __shared__ float SOk[128], SOv[128];
  __shared__ float G[2][16];
  __shared__ float KV[48];

  if (tid < 176){
    const float* p = sg + (c*32 + r)*SGSTRIDE_;
    X[tid] = p[tid] / p[176];
  }
  __syncthreads();

  if (tid < 32){
    int path = tid >> 4, i = tid & 15;
    fptr wh = path ? vv_wh : k_wh;
    float h0=0.f, h1=0.f, h2=0.f;
    #pragma unroll
    for (int j = 0; j < 16; j++){
      float w = wh[j*16 + i];
      h0 = fmaf(X[128 + j*3 + 0], w, h0);
      h1 = fmaf(X[128 + j*3 + 1], w, h1);
      h2 = fmaf(X[128 + j*3 + 2], w, h2);
    }
    VH[path][ 0 + i] = h0; VH[path][16 + i] = h1; VH[path][32 + i] = h2;
    VN[path][i] = sqrtf(fmaxf(h0*h0 + h1*h1 + h2*h2, 1e-8f));
  }
  __syncthreads();

  {
    int path = tid >> 7, col = tid & 127;
    fptr W  = path ? vv_ws_w : k_ws_w;
    fptr Bb = path ? vv_ws_b : k_ws_b;
    float so = Bb[col];
    for (int j = 0; j < 128; j++) so = fmaf(X[j], W[j*128 + col], so);
    #pragma unroll
    for (int i = 0; i < 16; i++)  so = fmaf(VN[path][i], W[(128+i)*128 + col], so);
    (path ? SOv : SOk)[col] = so;
  }
  __syncthreads();

  if (tid < 32){
    int path = tid >> 4, g = tid & 15;
    fptr Wsv = path ? vv_wsv_w : k_wsv_w;
    fptr Bsv = path ? vv_wsv_b : k_wsv_b;
    const float* SOp = path ? SOv : SOk;
    float ga = Bsv[g];
    for (int o = 0; o < 128; o++)
      ga = fmaf(sigm(SOp[o]), Wsv[o*16 + g], ga);
    G[path][g] = sigm(ga);
  } else if (tid < 36){
    int h = tid - 32;
    float e = 0.f;
    #pragma unroll
    for (int t = 0; t < 32; t++){
      float so = SOk[h*32 + t];
      e = fmaf(so * sigm(so), attn_ws_w[32 + t], e);
    }
    tek[(r*2 + c)*4 + h] = e;
  } else if (tid >= 64 && tid < 192){
    int o = tid - 64;
    float so = SOv[o];
    tvs[(r*2 + c)*128 + o] = so * sigm(so);
  }
  __syncthreads();

  if (tid < 96){
    int path = tid / 48, k = tid % 48, i = k / 3, d = k - i*3;
    fptr Wv = path ? vv_wv : k_wv;
    float vo = 0.f;
    #pragma unroll
    for (int j = 0; j < 16; j++)
      vo = fmaf(VH[path][d*16 + j], Wv[j*16 + i], vo);
    float gv = vo * G[path][i];
    if (path == 0) KV[k] = gv;
    else {
      int h = i >> 2, ii = i & 3;
      tvv[(((r*2 + c)*4 + h)*4 + ii)*3 + d] = gv;
    }
  }
  __syncthreads();

  if (tid < 96){
    int h = tid / 24, rem = tid % 24, d = rem >> 3, ee = rem & 7;
    float a = 0.f;
    #pragma unroll
    for (int i = 0; i < 4; i++)
      a = fmaf(KV[(h*4 + i)*3 + d], attn_wh[(4 + i)*8 + ee], a);
    tkh[((r*2 + c)*4 + h)*24 + d*8 + ee] = a;
  }
}

// ================= kAttn: 256 thr / 64 rows / 313 blocks ====================
// Body identical to R9/R13 (scalar KH broadcast, float4 VS/VV, no-max softmax).
__global__ __launch_bounds__(256, 1) void kAttn(
    const float* __restrict__ eqh,
    const float* __restrict__ tkh, const float* __restrict__ tek,
    const float* __restrict__ tvs, const float* __restrict__ tvv,
    fptr attn_ws_w, fptr attn_ws_b,
    float* __restrict__ out)
{
  __shared__ __align__(16) float KH[6144];
  __shared__ __align__(16) float EK[256];
  __shared__ __align__(16) float VS[256*36];
  __shared__ __align__(16) float VVt[3072];
  const int tid = threadIdx.x;

  for (int i = tid; i < 6144; i += 256) KH[i] = tkh[i];
  if (tid < 256) EK[tid] = tek[tid];
  for (int i = tid; i < 8192; i += 256){ int base = i >> 5, t = i & 31; VS[base*36 + t] = tvs[i]; }
  for (int i = tid; i < 3072; i += 256) VVt[i] = tvv[i];

  float wsn[8];
  #pragma unroll
  for (int ee = 0; ee < 8; ee++) wsn[ee] = attn_ws_w[64 + ee];
  const float wb = attn_ws_b[0];
  __syncthreads();

  const int row = blockIdx.x*64 + (tid >> 2);
  const int h = tid & 3;
  if (row < NC_){
    const int c = row & 1;
    const float eq = eqh[row*100 + h];
    float qh[24];
    {
      const float4* qp = (const float4*)&eqh[row*100 + 8 + h*24];
      #pragma unroll
      for (int k = 0; k < 6; k++){
        float4 t4 = qp[k];
        qh[k*4+0] = t4.x; qh[k*4+1] = t4.y; qh[k*4+2] = t4.z; qh[k*4+3] = t4.w;
      }
    }
    float4 accs4[8];
    float4 accv4[3];
    #pragma unroll
    for (int q = 0; q < 8; q++) accs4[q] = make_float4(0.f,0.f,0.f,0.f);
    #pragma unroll
    for (int q = 0; q < 3; q++) accv4[q] = make_float4(0.f,0.f,0.f,0.f);
    float den = 0.f;

    #pragma unroll
    for (int r = 0; r < 32; r++){
      const int base = (r*2 + c)*4 + h;
      const float* khp = &KH[base*24];
      float en = 0.f;
      #pragma unroll
      for (int ee = 0; ee < 8; ee++){
        float a0 = qh[ee]      + khp[ee];
        float a1 = qh[8 + ee]  + khp[8 + ee];
        float a2 = qh[16 + ee] + khp[16 + ee];
        en = fmaf(sqrtf(fmaxf(a0*a0 + a1*a1 + a2*a2, 1e-8f)), wsn[ee], en);
      }
      const float w = __expf((eq + EK[base] + en + wb) * 0.17677669529663687f);
      den += w;
      const float4* vp4 = (const float4*)&VS[base*36];
      #pragma unroll
      for (int q = 0; q < 8; q++){
        float4 t4 = vp4[q];
        accs4[q].x = fmaf(w, t4.x, accs4[q].x);
        accs4[q].y = fmaf(w, t4.y, accs4[q].y);
        accs4[q].z = fmaf(w, t4.z, accs4[q].z);
        accs4[q].w = fmaf(w, t4.w, accs4[q].w);
      }
      const float4* vv4 = (const float4*)&VVt[base*12];
      #pragma unroll
      for (int q = 0; q < 3; q++){
        float4 t4 = vv4[q];
        accv4[q].x = fmaf(w, t4.x, accv4[q].x);
        accv4[q].y = fmaf(w, t4.y, accv4[q].y);
        accv4[q].z = fmaf(w, t4.z, accv4[q].z);
        accv4[q].w = fmaf(w, t4.w, accv4[q].w);
      }
    }
    const float inv = 1.f / den;
    float4* po = (float4*)&out[row*128 + h*32];
    #pragma unroll
    for (int q = 0; q < 8; q++){
      float4 t4 = accs4[q];
      t4.x *= inv; t4.y *= inv; t4.z *= inv; t4.w *= inv;
      po[q] = t4;
    }
    float4* pv = (float4*)&out[NC_*128 + row*48 + h*12];
    #pragma unroll
    for (int q = 0; q < 3; q++){
      float4 t4 = accv4[q];
      t4.x *= inv; t4.y *= inv; t4.z *= inv; t4.w *= inv;
      pv[q] = t4;
    }
  }
}

extern "C" void kernel_launch(void* const* d_in, const int* in_sizes, int n_in,
                              void* d_out, int out_size, void* d_ws, size_t ws_size,
                              hipStream_t stream)
{
  fptr s        = (fptr)d_in[0];
  fptr v        = (fptr)d_in[1];
  fptr wp_wh    = (fptr)d_in[2];
  fptr wp_ws_w  = (fptr)d_in[3];
  fptr wp_ws_b  = (fptr)d_in[4];
  fptr q_wh     = (fptr)d_in[5];
  fptr q_ws_w   = (fptr)d_in[6];
  fptr q_ws_b   = (fptr)d_in[7];
  fptr q_wv     = (fptr)d_in[8];
  fptr q_wsv_w  = (fptr)d_in[9];
  fptr q_wsv_b  = (fptr)d_in[10];
  fptr k_wh     = (fptr)d_in[11];
  fptr k_ws_w   = (fptr)d_in[12];
  fptr k_ws_b   = (fptr)d_in[13];
  fptr k_wv     = (fptr)d_in[14];
  fptr k_wsv_w  = (fptr)d_in[15];
  fptr k_wsv_b  = (fptr)d_in[16];
  fptr vv_wh    = (fptr)d_in[17];
  fptr vv_ws_w  = (fptr)d_in[18];
  fptr vv_ws_b  = (fptr)d_in[19];
  fptr vv_wv    = (fptr)d_in[20];
  fptr vv_wsv_w = (fptr)d_in[21];
  fptr vv_wsv_b = (fptr)d_in[22];
  fptr attn_wh  = (fptr)d_in[23];
  fptr attn_ws_w= (fptr)d_in[24];
  fptr attn_ws_b= (fptr)d_in[25];

  float* ws   = (float*)d_ws;
  float* pexp = ws + OFF_LG;
  float* eqh  = ws + OFF_EQH;
  float* sg   = ws + OFF_SG;
  float* tkh  = ws + OFF_TKH;
  float* tek  = ws + OFF_TEK;
  float* tvs  = ws + OFF_TVS;
  float* tvv  = ws + OFF_TVV;

  kA<<<NC_/8, 256, 0, stream>>>(s, v, wp_wh, wp_ws_w, wp_ws_b,
                                q_wh, q_ws_w, q_ws_b, q_wv, q_wsv_w, q_wsv_b,
                                attn_wh, attn_ws_w, pexp, eqh, sg);
  kAccum<<<800, 256, 0, stream>>>(pexp, s, v, sg);
  kSmall<<<64, 256, 0, stream>>>(sg,
                                 k_wh, k_ws_w, k_ws_b, k_wv, k_wsv_w, k_wsv_b,
                                 vv_wh, vv_ws_w, vv_ws_b, vv_wv, vv_wsv_w, vv_wsv_b,
                                 attn_wh, attn_ws_w, tkh, tek, tvs, tvv);
  kAttn<<<(NC_ + 63)/64, 256, 0, stream>>>(eqh, tkh, tek, tvs, tvv,
                                           attn_ws_w, attn_ws_b, (float*)d_out);
}

// Round 15
// 246.409 us; speedup vs baseline: 1.0832x; 1.0832x over previous
//
#include <hip/hip_runtime.h>
#include <hip/hip_bf16.h>

// GVPDynamicProjection: N=10000, C=2, SI=128, VI=16, H=4, R=32, SH=32, VH=4
// Inputs/outputs: float32. R15 vs R13 (240.8 us) / R14 (266.9, kAttn 103-128):
// R14 proved kAttn is WAVE-STARVED (80000 threads = 1250 waves = 1.2/SIMD
// chip-wide; 256thr shape gave 1 wave/SIMD on most CUs). R15: split the
// 32-iteration r-loop across lane PAIRS (tid^1) -> 2500 waves, grid 313 covers
// all CUs at >=8 waves/CU; combine partials with 45 shfl_xor+add (no-max
// softmax => partial sums combine exactly). Same per-thread state (~100 VGPR,
// under the R8/R10-measured spill wall). kA/kAccum/kSmall byte-identical R13.

#define N_  10000
#define C_  2
#define SI_ 128
#define VI_ 16
#define H_  4
#define R_  32
#define SH_ 32
#define VH_ 4
#define NC_ (N_*C_)

typedef const float* __restrict__ fptr;

__device__ __forceinline__ float sigm(float x){ return 1.f/(1.f+__expf(-x)); }

// ---------------- ws layout (float offsets) ----------------
#define OFF_LG   0
#define OFF_EQH  640000
#define OFF_SG   2640000
#define OFF_TKH  2651520
#define OFF_TEK  2657664
#define OFF_TVS  2657920
#define OFF_TVV  2666112

#define SGSTRIDE_ 180

// ================= kernel A: per-row logits + q-path =================
// 256 threads, 8 rows/block; grid = NC_/8 = 2500  (parked at ~50us plateau)
__global__ __launch_bounds__(256) void kA(
    fptr s, fptr v,
    fptr wp_wh, fptr wp_ws_w, fptr wp_ws_b,
    fptr q_wh, fptr q_ws_w, fptr q_ws_b, fptr q_wv, fptr q_wsv_w, fptr q_wsv_b,
    fptr attn_wh, fptr attn_ws_w,
    float* __restrict__ pexp, float* __restrict__ eqh,
    float* __restrict__ sgz)
{
  __shared__ __align__(16) float ARENA[160*12];
  __shared__ __align__(16) float VVs[8*48];
  __shared__ __align__(16) float VHQ[8*48];
  __shared__ __align__(16) float SO[8*128];
  __shared__ __align__(16) float GATE[8*16];
  __shared__ __align__(16) float QV[8*48];
  float* const XT  = ARENA;
  float* const SIG = ARENA;

  const int tid  = threadIdx.x;
  const int row0 = blockIdx.x * 8;

  if (blockIdx.x == 0){
    for (int i = tid; i < 64*SGSTRIDE_; i += 256) sgz[i] = 0.f;
  }

  for (int idx = tid; idx < 8*128; idx += 256){
    int r = idx >> 7, j = idx & 127;
    XT[j*12 + r] = s[(row0+r)*128 + j];
  }
  for (int idx = tid; idx < 8*48; idx += 256){
    int r = idx / 48, k = idx - r*48;
    VVs[r*48 + k] = v[(row0+r)*48 + k];
  }
  __syncthreads();

  {
    int r = tid >> 5, ii = tid & 31, path = ii >> 4, i = ii & 15;
    fptr wh = path ? wp_wh : q_wh;
    float h0=0.f, h1=0.f, h2=0.f;
    #pragma unroll
    for (int j = 0; j < 16; j++){
      float w = wh[j*16 + i];
      h0 = fmaf(VVs[r*48 + j*3 + 0], w, h0);
      h1 = fmaf(VVs[r*48 + j*3 + 1], w, h1);
      h2 = fmaf(VVs[r*48 + j*3 + 2], w, h2);
    }
    float vn = sqrtf(fmaxf(h0*h0 + h1*h1 + h2*h2, 1e-8f));
    if (!path){
      VHQ[r*48 +  0 + i] = h0;
      VHQ[r*48 + 16 + i] = h1;
      VHQ[r*48 + 32 + i] = h2;
      XT[(128+i)*12 + r] = vn;
    } else {
      XT[(144+i)*12 + r] = vn;
    }
  }
  __syncthreads();

  const int colA = tid & 127, rgA = tid >> 7;
  float acc[4];
  {
    float bqs = q_ws_b[colA];
    #pragma unroll
    for (int k = 0; k < 4; k++) acc[k] = bqs;
    #pragma unroll 8
    for (int j = 0; j < 144; j++){
      float w = q_ws_w[j*128 + colA];
      float4 x0 = *(const float4*)&XT[j*12 + rgA*4];
      acc[0] = fmaf(x0.x, w, acc[0]); acc[1] = fmaf(x0.y, w, acc[1]);
      acc[2] = fmaf(x0.z, w, acc[2]); acc[3] = fmaf(x0.w, w, acc[3]);
    }
  }
  {
    const int col = tid & 31, rg = tid >> 5;
    float a0 = wp_ws_b[col];
    #pragma unroll 8
    for (int j = 0; j < 144; j++){
      int jj = (j < 128) ? j : (j + 16);
      a0 = fmaf(XT[jj*12 + rg], wp_ws_w[j*32 + col], a0);
    }
    const int c = rg & 1, n = (row0 + rg) >> 1;
    pexp[(c*32 + col)*N_ + n] = __expf(a0);
  }
  __syncthreads();

  #pragma unroll
  for (int k = 0; k < 4; k++){
    float so = acc[k];
    float sg_ = sigm(so);
    SIG[(rgA*4 + k)*128 + colA] = sg_;
    SO [(rgA*4 + k)*128 + colA] = so * sg_;
  }
  __syncthreads();

  if (tid < 128){
    const int r = tid >> 4, g = tid & 15;
    float ga = q_wsv_b[g];
    #pragma unroll 8
    for (int o = 0; o < 128; o += 4){
      float4 s4 = *(const float4*)&SIG[r*128 + o];
      ga = fmaf(s4.x, q_wsv_w[(o+0)*16 + g], ga);
      ga = fmaf(s4.y, q_wsv_w[(o+1)*16 + g], ga);
      ga = fmaf(s4.z, q_wsv_w[(o+2)*16 + g], ga);
      ga = fmaf(s4.w, q_wsv_w[(o+3)*16 + g], ga);
    }
    GATE[r*16 + g] = sigm(ga);
  } else if (tid < 160){
    const int t2 = tid - 128, r = t2 >> 2, h = t2 & 3;
    float e = 0.f;
    #pragma unroll
    for (int t = 0; t < 32; t++)
      e = fmaf(SO[r*128 + h*32 + t], attn_ws_w[t], e);
    eqh[(row0 + r)*100 + h] = e;
  }
  __syncthreads();

  for (int t = tid; t < 8*48; t += 256){
    int r = t / 48, k = t - r*48, i = k / 3, d = k - i*3;
    float a = 0.f;
    #pragma unroll
    for (int j = 0; j < 16; j++)
      a = fmaf(VHQ[r*48 + d*16 + j], q_wv[j*16 + i], a);
    QV[r*48 + k] = a * GATE[r*16 + i];
  }
  __syncthreads();

  for (int t = tid; t < 8*96; t += 256){
    int r = t / 96, k = t - r*96;
    int h = k / 24, rem = k - h*24, d = rem >> 3, ee = rem & 7;
    float a = 0.f;
    #pragma unroll
    for (int i = 0; i < 4; i++)
      a = fmaf(QV[r*48 + (h*4 + i)*3 + d], attn_wh[i*8 + ee], a);
    eqh[(row0 + r)*100 + 8 + k] = a;
  }
}

// ===== kAccum: weighted sums via atomics, 800 blocks = 3200 waves ==========
__global__ __launch_bounds__(256) void kAccum(const float* __restrict__ pexp,
                                              fptr s, fptr v,
                                              float* __restrict__ sg)
{
  const int b = blockIdx.x;
  const int c = b & 1, ah = (b >> 1) & 1, chunk = b >> 2;
  const int n0 = chunk * 50;
  const int tid = threadIdx.x;
  const int ag = tid >> 6, dl = tid & 63;
  const int abase = ah*16 + ag*4;

  const float* pb = pexp + (c*32 + abase)*N_;
  float acc[4][3] = {};
  float dn[4] = {};

  #pragma unroll 2
  for (int n = n0; n < n0 + 50; n++){
    const int rc = n*2 + c;
    float pw[4];
    #pragma unroll
    for (int aa = 0; aa < 4; aa++){
      pw[aa] = pb[aa*N_ + n];
      dn[aa] += pw[aa];
    }
    #pragma unroll
    for (int dd = 0; dd < 3; dd++){
      int d = dl + 64*dd;
      if (d < 176){
        float xv = (d < 128) ? s[rc*128 + d] : v[rc*48 + d - 128];
        #pragma unroll
        for (int aa = 0; aa < 4; aa++)
          acc[aa][dd] = fmaf(pw[aa], xv, acc[aa][dd]);
      }
    }
  }
  #pragma unroll
  for (int aa = 0; aa < 4; aa++){
    const int base = (c*32 + abase + aa)*SGSTRIDE_;
    #pragma unroll
    for (int dd = 0; dd < 3; dd++){
      int d = dl + 64*dd;
      if (d < 176) atomicAdd(&sg[base + d], acc[aa][dd]);
    }
    if (dl == 0) atomicAdd(&sg[base + 176], dn[aa]);
  }
}

// ================= kSmall: normalize + k/vv GVP + attn tables ===============
__global__ __launch_bounds__(256) void kSmall(
    const float* __restrict__ sg,
    fptr k_wh, fptr k_ws_w, fptr k_ws_b, fptr k_wv, fptr k_wsv_w, fptr k_wsv_b,
    fptr vv_wh, fptr vv_ws_w, fptr vv_ws_b, fptr vv_wv, fptr vv_wsv_w, fptr vv_wsv_b,
    fptr attn_wh, fptr attn_ws_w,
    float* __restrict__ tkh, float* __restrict__ tek,
    float* __restrict__ tvs, float* __restrict__ tvv)
{
  const int b = blockIdx.x, r = b >> 1, c = b & 1;
  const int tid = threadIdx.x;
  __shared__ float X[176];
  __shared__ float VN[2][16];
  __shared__ float VH[2][48];
  __shared__ float SOk[128], SOv[128];
  __shared__ float G[2][16];
  __shared__ float KV[48];

  if (tid < 176){
    const float* p = sg + (c*32 + r)*SGSTRIDE_;
    X[tid] = p[tid] / p[176];
  }
  __syncthreads();

  if (tid < 32){
    int path = tid >> 4, i = tid & 15;
    fptr wh = path ? vv_wh : k_wh;
    float h0=0.f, h1=0.f, h2=0.f;
    #pragma unroll
    for (int j = 0; j < 16; j++){
      float w = wh[j*16 + i];
      h0 = fmaf(X[128 + j*3 + 0], w, h0);
      h1 = fmaf(X[128 + j*3 + 1], w, h1);
      h2 = fmaf(X[128 + j*3 + 2], w, h2);
    }
    VH[path][ 0 + i] = h0; VH[path][16 + i] = h1; VH[path][32 + i] = h2;
    VN[path][i] = sqrtf(fmaxf(h0*h0 + h1*h1 + h2*h2, 1e-8f));
  }
  __syncthreads();

  {
    int path = tid >> 7, col = tid & 127;
    fptr W  = path ? vv_ws_w : k_ws_w;
    fptr Bb = path ? vv_ws_b : k_ws_b;
    float so = Bb[col];
    for (int j = 0; j < 128; j++) so = fmaf(X[j], W[j*128 + col], so);
    #pragma unroll
    for (int i = 0; i < 16; i++)  so = fmaf(VN[path][i], W[(128+i)*128 + col], so);
    (path ? SOv : SOk)[col] = so;
  }
  __syncthreads();

  if (tid < 32){
    int path = tid >> 4, g = tid & 15;
    fptr Wsv = path ? vv_wsv_w : k_wsv_w;
    fptr Bsv = path ? vv_wsv_b : k_wsv_b;
    const float* SOp = path ? SOv : SOk;
    float ga = Bsv[g];
    for (int o = 0; o < 128; o++)
      ga = fmaf(sigm(SOp[o]), Wsv[o*16 + g], ga);
    G[path][g] = sigm(ga);
  } else if (tid < 36){
    int h = tid - 32;
    float e = 0.f;
    #pragma unroll
    for (int t = 0; t < 32; t++){
      float so = SOk[h*32 + t];
      e = fmaf(so * sigm(so), attn_ws_w[32 + t], e);
    }
    tek[(r*2 + c)*4 + h] = e;
  } else if (tid >= 64 && tid < 192){
    int o = tid - 64;
    float so = SOv[o];
    tvs[(r*2 + c)*128 + o] = so * sigm(so);
  }
  __syncthreads();

  if (tid < 96){
    int path = tid / 48, k = tid % 48, i = k / 3, d = k - i*3;
    fptr Wv = path ? vv_wv : k_wv;
    float vo = 0.f;
    #pragma unroll
    for (int j = 0; j < 16; j++)
      vo = fmaf(VH[path][d*16 + j], Wv[j*16 + i], vo);
    float gv = vo * G[path][i];
    if (path == 0) KV[k] = gv;
    else {
      int h = i >> 2, ii = i & 3;
      tvv[(((r*2 + c)*4 + h)*4 + ii)*3 + d] = gv;
    }
  }
  __syncthreads();

  if (tid < 96){
    int h = tid / 24, rem = tid % 24, d = rem >> 3, ee = rem & 7;
    float a = 0.f;
    #pragma unroll
    for (int i = 0; i < 4; i++)
      a = fmaf(KV[(h*4 + i)*3 + d], attn_wh[(4 + i)*8 + ee], a);
    tkh[((r*2 + c)*4 + h)*24 + d*8 + ee] = a;
  }
}

// ================= kAttn: split-r lane pairs ================================
// 512 thr = 64 rows x 4 h x 2 halves; grid 313 (all CUs); 2500 total waves.
// Each half accumulates 16 of 32 KV rows; 45 shfl_xor(+) combine; half 0 stores.
__global__ __launch_bounds__(512, 1) void kAttn(
    const float* __restrict__ eqh,
    const float* __restrict__ tkh, const float* __restrict__ tek,
    const float* __restrict__ tvs, const float* __restrict__ tvv,
    fptr attn_ws_w, fptr attn_ws_b,
    float* __restrict__ out)
{
  __shared__ __align__(16) float KH[6144];
  __shared__ __align__(16) float EK[256];
  __shared__ __align__(16) float VS[256*36];
  __shared__ __align__(16) float VVt[3072];
  const int tid = threadIdx.x;

  for (int i = tid; i < 6144; i += 512) KH[i] = tkh[i];
  if (tid < 256) EK[tid] = tek[tid];
  for (int i = tid; i < 8192; i += 512){ int base = i >> 5, t = i & 31; VS[base*36 + t] = tvs[i]; }
  for (int i = tid; i < 3072; i += 512) VVt[i] = tvv[i];

  float wsn[8];
  #pragma unroll
  for (int ee = 0; ee < 8; ee++) wsn[ee] = attn_ws_w[64 + ee];
  const float wb = attn_ws_b[0];
  __syncthreads();

  const int row  = blockIdx.x*64 + (tid >> 3);
  const int h    = (tid >> 1) & 3;
  const int half = tid & 1;
  if (row < NC_){
    const int c = row & 1;
    const float eq = eqh[row*100 + h];
    float qh[24];
    {
      const float4* qp = (const float4*)&eqh[row*100 + 8 + h*24];
      #pragma unroll
      for (int k = 0; k < 6; k++){
        float4 t4 = qp[k];
        qh[k*4+0] = t4.x; qh[k*4+1] = t4.y; qh[k*4+2] = t4.z; qh[k*4+3] = t4.w;
      }
    }
    float4 accs4[8];
    float4 accv4[3];
    #pragma unroll
    for (int q = 0; q < 8; q++) accs4[q] = make_float4(0.f,0.f,0.f,0.f);
    #pragma unroll
    for (int q = 0; q < 3; q++) accv4[q] = make_float4(0.f,0.f,0.f,0.f);
    float den = 0.f;

    const int r0 = half * 16;
    #pragma unroll
    for (int rr = 0; rr < 16; rr++){
      const int r = r0 + rr;
      const int base = (r*2 + c)*4 + h;
      const float* khp = &KH[base*24];
      float en = 0.f;
      #pragma unroll
      for (int ee = 0; ee < 8; ee++){
        float a0 = qh[ee]      + khp[ee];
        float a1 = qh[8 + ee]  + khp[8 + ee];
        float a2 = qh[16 + ee] + khp[16 + ee];
        en = fmaf(sqrtf(fmaxf(a0*a0 + a1*a1 + a2*a2, 1e-8f)), wsn[ee], en);
      }
      // no max-subtraction: |ev| small (0.177-scaled O(1) logits), f32-safe;
      // partial sums over disjoint r combine exactly via lane-pair reduce.
      const float w = __expf((eq + EK[base] + en + wb) * 0.17677669529663687f);
      den += w;
      const float4* vp4 = (const float4*)&VS[base*36];
      #pragma unroll
      for (int q = 0; q < 8; q++){
        float4 t4 = vp4[q];
        accs4[q].x = fmaf(w, t4.x, accs4[q].x);
        accs4[q].y = fmaf(w, t4.y, accs4[q].y);
        accs4[q].z = fmaf(w, t4.z, accs4[q].z);
        accs4[q].w = fmaf(w, t4.w, accs4[q].w);
      }
      const float4* vv4 = (const float4*)&VVt[base*12];
      #pragma unroll
      for (int q = 0; q < 3; q++){
        float4 t4 = vv4[q];
        accv4[q].x = fmaf(w, t4.x, accv4[q].x);
        accv4[q].y = fmaf(w, t4.y, accv4[q].y);
        accv4[q].z = fmaf(w, t4.z, accv4[q].z);
        accv4[q].w = fmaf(w, t4.w, accv4[q].w);
      }
    }

    // lane-pair combine (partner lane tid^1 shares (row,h), is active too)
    den += __shfl_xor(den, 1);
    #pragma unroll
    for (int q = 0; q < 8; q++){
      accs4[q].x += __shfl_xor(accs4[q].x, 1);
      accs4[q].y += __shfl_xor(accs4[q].y, 1);
      accs4[q].z += __shfl_xor(accs4[q].z, 1);
      accs4[q].w += __shfl_xor(accs4[q].w, 1);
    }
    #pragma unroll
    for (int q = 0; q < 3; q++){
      accv4[q].x += __shfl_xor(accv4[q].x, 1);
      accv4[q].y += __shfl_xor(accv4[q].y, 1);
      accv4[q].z += __shfl_xor(accv4[q].z, 1);
      accv4[q].w += __shfl_xor(accv4[q].w, 1);
    }

    if (half == 0){
      const float inv = 1.f / den;
      float4* po = (float4*)&out[row*128 + h*32];
      #pragma unroll
      for (int q = 0; q < 8; q++){
        float4 t4 = accs4[q];
        t4.x *= inv; t4.y *= inv; t4.z *= inv; t4.w *= inv;
        po[q] = t4;
      }
      float4* pv = (float4*)&out[NC_*128 + row*48 + h*12];
      #pragma unroll
      for (int q = 0; q < 3; q++){
        float4 t4 = accv4[q];
        t4.x *= inv; t4.y *= inv; t4.z *= inv; t4.w *= inv;
        pv[q] = t4;
      }
    }
  }
}

extern "C" void kernel_launch(void* const* d_in, const int* in_sizes, int n_in,
                              void* d_out, int out_size, void* d_ws, size_t ws_size,
                              hipStream_t stream)
{
  fptr s        = (fptr)d_in[0];
  fptr v        = (fptr)d_in[1];
  fptr wp_wh    = (fptr)d_in[2];
  fptr wp_ws_w  = (fptr)d_in[3];
  fptr wp_ws_b  = (fptr)d_in[4];
  fptr q_wh     = (fptr)d_in[5];
  fptr q_ws_w   = (fptr)d_in[6];
  fptr q_ws_b   = (fptr)d_in[7];
  fptr q_wv     = (fptr)d_in[8];
  fptr q_wsv_w  = (fptr)d_in[9];
  fptr q_wsv_b  = (fptr)d_in[10];
  fptr k_wh     = (fptr)d_in[11];
  fptr k_ws_w   = (fptr)d_in[12];
  fptr k_ws_b   = (fptr)d_in[13];
  fptr k_wv     = (fptr)d_in[14];
  fptr k_wsv_w  = (fptr)d_in[15];
  fptr k_wsv_b  = (fptr)d_in[16];
  fptr vv_wh    = (fptr)d_in[17];
  fptr vv_ws_w  = (fptr)d_in[18];
  fptr vv_ws_b  = (fptr)d_in[19];
  fptr vv_wv    = (fptr)d_in[20];
  fptr vv_wsv_w = (fptr)d_in[21];
  fptr vv_wsv_b = (fptr)d_in[22];
  fptr attn_wh  = (fptr)d_in[23];
  fptr attn_ws_w= (fptr)d_in[24];
  fptr attn_ws_b= (fptr)d_in[25];

  float* ws   = (float*)d_ws;
  float* pexp = ws + OFF_LG;
  float* eqh  = ws + OFF_EQH;
  float* sg   = ws + OFF_SG;
  float* tkh  = ws + OFF_TKH;
  float* tek  = ws + OFF_TEK;
  float* tvs  = ws + OFF_TVS;
  float* tvv  = ws + OFF_TVV;

  kA<<<NC_/8, 256, 0, stream>>>(s, v, wp_wh, wp_ws_w, wp_ws_b,
                                q_wh, q_ws_w, q_ws_b, q_wv, q_wsv_w, q_wsv_b,
                                attn_wh, attn_ws_w, pexp, eqh, sg);
  kAccum<<<800, 256, 0, stream>>>(pexp, s, v, sg);
  kSmall<<<64, 256, 0, stream>>>(sg,
                                 k_wh, k_ws_w, k_ws_b, k_wv, k_wsv_w, k_wsv_b,
                                 vv_wh, vv_ws_w, vv_ws_b, vv_wv, vv_wsv_w, vv_wsv_b,
                                 attn_wh, attn_ws_w, tkh, tek, tvs, tvv);
  kAttn<<<(NC_ + 63)/64, 512, 0, stream>>>(eqh, tkh, tek, tvs, tvv,
                                           attn_ws_w, attn_ws_b, (float*)d_out);
}